// Round 5
// baseline (817.372 us; speedup 1.0000x reference)
//
#include <hip/hip_runtime.h>
#include <hip/hip_bf16.h>

#define N_NODES 100000
#define N_EDGES 1200000
#define G_GRAPHS 128
#define CAP 64      // max in-degree capacity (Poisson mean 12; max deg @1e-10 ~ 40)
#define WP 68       // padded LDS row stride (floats) to break transpose-store bank conflicts

// ---------------- CSR build (by dst) ----------------
__global__ void scatter_k(const int* __restrict__ ei, int* __restrict__ cnt,
                          int* __restrict__ adj) {
    int e = blockIdx.x * 256 + threadIdx.x;
    if (e >= N_EDGES) return;
    int s = ei[e];             // src
    int d = ei[N_EDGES + e];   // dst
    s = min(max(s, 0), N_NODES - 1);
    d = min(max(d, 0), N_NODES - 1);
    int pos = atomicAdd(&cnt[d], 1);
    if (pos < CAP) adj[d * CAP + pos] = s;
}

// pad each adjacency row to a multiple of 8 with sentinel N_NODES (zero h-row)
// so agg_k runs a pure 8-wide loop with no divergent tail.
__global__ void pad_k(int* __restrict__ cnt, int* __restrict__ adj) {
    int n = blockIdx.x * 256 + threadIdx.x;
    if (n >= N_NODES) return;
    int c = min(cnt[n], CAP);
    int p = min((c + 7) & ~7, CAP);
    for (int i = c; i < p; ++i) adj[n * CAP + i] = N_NODES;
    cnt[n] = p;
}

// ---------------- embedding gather ----------------
__global__ void embed_k(const int* __restrict__ x, const float4* __restrict__ emb,
                        float4* __restrict__ h) {
    int t = blockIdx.x * 256 + threadIdx.x;
    if (t >= N_NODES * 16) return;
    int n = t >> 4, q = t & 15;
    h[n * 16 + q] = emb[x[n] * 16 + q];
}

__device__ __forceinline__ void f4add(float4& a, const float4 b) {
    a.x += b.x; a.y += b.y; a.z += b.z; a.w += b.w;
}

// ---------------- neighbor aggregation + self term (gather, no atomics) -------
// out[n] = h[n] + sum_{s in adj[n]} h[s].  Pure 8-wide: 8 outstanding gathers.
__global__ void agg_k(const float4* __restrict__ h, const int* __restrict__ adj,
                      const int* __restrict__ cnt, float4* __restrict__ agg) {
    int t = blockIdx.x * 256 + threadIdx.x;
    int n = t >> 4, q = t & 15;     // 16 lanes per node, float4 per lane
    if (n >= N_NODES) return;
    int deg = cnt[n];               // multiple of 8, <= CAP
    const int4* al4 = (const int4*)(adj + n * CAP);
    float4 a0 = h[n * 16 + q];      // self term fused
    float4 a1 = make_float4(0.f, 0.f, 0.f, 0.f);
    float4 a2 = a1, a3 = a1, a4 = a1, a5 = a1, a6 = a1, a7 = a1;
    int d8 = deg >> 3;
    for (int i = 0; i < d8; ++i) {
        int4 sa = al4[2 * i];
        int4 sb = al4[2 * i + 1];
        float4 v0 = h[sa.x * 16 + q];
        float4 v1 = h[sa.y * 16 + q];
        float4 v2 = h[sa.z * 16 + q];
        float4 v3 = h[sa.w * 16 + q];
        float4 v4 = h[sb.x * 16 + q];
        float4 v5 = h[sb.y * 16 + q];
        float4 v6 = h[sb.z * 16 + q];
        float4 v7 = h[sb.w * 16 + q];
        f4add(a0, v0); f4add(a1, v1); f4add(a2, v2); f4add(a3, v3);
        f4add(a4, v4); f4add(a5, v5); f4add(a6, v6); f4add(a7, v7);
    }
    f4add(a0, a1); f4add(a2, a3); f4add(a4, a5); f4add(a6, a7);
    f4add(a0, a2); f4add(a4, a6); f4add(a0, a4);
    agg[n * 16 + q] = a0;
}

// 64-dot against LDS-transposed weight row j (broadcast reads).
__device__ __forceinline__ float dot64(const float* wt, int j, const float* t) {
    const float4* w = (const float4*)(wt + j * WP);
    float a0 = 0.f, a1 = 0.f, a2 = 0.f, a3 = 0.f;
    #pragma unroll
    for (int kq = 0; kq < 16; ++kq) {
        float4 wv = w[kq];
        a0 += t[4 * kq + 0] * wv.x;
        a1 += t[4 * kq + 1] * wv.y;
        a2 += t[4 * kq + 2] * wv.z;
        a3 += t[4 * kq + 3] * wv.w;
    }
    return (a0 + a1) + (a2 + a3);
}

__device__ __forceinline__ float elu(float v) { return v > 0.f ? v : expm1f(v); }

// ---------------- MLP phase A: io <- elu(BNaffine(io @ W1)), in-place --------
// Live set: t[64] + 4-output buffer -> ~75 VGPRs, no spill at any cap.
__global__ void __launch_bounds__(256) mlpA_k(float* __restrict__ io,
    const float* __restrict__ W1, const float* __restrict__ b1,
    const float* __restrict__ g,  const float* __restrict__ be) {
    __shared__ float wt[64 * WP];
    __shared__ float bb[64];
    int tid = threadIdx.x;
    const float inv = rsqrtf(1.0f + 1e-5f);
    for (int idx = tid; idx < 4096; idx += 256) {
        int k = idx >> 6, j = idx & 63;
        wt[j * WP + k] = W1[idx] * (g[j] * inv);
    }
    if (tid < 64) bb[tid] = b1[tid] * (g[tid] * inv) + be[tid];
    __syncthreads();
    int n = blockIdx.x * 256 + tid;
    if (n >= N_NODES) return;
    float t[64];
    float4* row = (float4*)(io + n * 64);
    #pragma unroll
    for (int q = 0; q < 16; ++q) {
        float4 v = row[q];
        t[4 * q + 0] = v.x; t[4 * q + 1] = v.y; t[4 * q + 2] = v.z; t[4 * q + 3] = v.w;
    }
    #pragma unroll
    for (int j4 = 0; j4 < 16; ++j4) {
        float d0 = elu(bb[4 * j4 + 0] + dot64(wt, 4 * j4 + 0, t));
        float d1 = elu(bb[4 * j4 + 1] + dot64(wt, 4 * j4 + 1, t));
        float d2 = elu(bb[4 * j4 + 2] + dot64(wt, 4 * j4 + 2, t));
        float d3 = elu(bb[4 * j4 + 3] + dot64(wt, 4 * j4 + 3, t));
        row[j4] = make_float4(d0, d1, d2, d3);   // row fully read above: in-place safe
    }
}

// ---------------- MLP phase B: h <- elu(y @ W2 + b2)  (outer GIN elu fused) ---
__global__ void __launch_bounds__(256) mlpB_k(const float* __restrict__ y,
    float* __restrict__ h,
    const float* __restrict__ W2, const float* __restrict__ b2) {
    __shared__ float wt[64 * WP];
    __shared__ float bb[64];
    int tid = threadIdx.x;
    for (int idx = tid; idx < 4096; idx += 256) {
        int k = idx >> 6, j = idx & 63;
        wt[j * WP + k] = W2[idx];
    }
    if (tid < 64) bb[tid] = b2[tid];
    __syncthreads();
    int n = blockIdx.x * 256 + tid;
    if (n >= N_NODES) return;
    float t[64];
    const float4* row = (const float4*)(y + n * 64);
    #pragma unroll
    for (int q = 0; q < 16; ++q) {
        float4 v = row[q];
        t[4 * q + 0] = v.x; t[4 * q + 1] = v.y; t[4 * q + 2] = v.z; t[4 * q + 3] = v.w;
    }
    float4* out = (float4*)(h + n * 64);
    #pragma unroll
    for (int j4 = 0; j4 < 16; ++j4) {
        float d0 = elu(bb[4 * j4 + 0] + dot64(wt, 4 * j4 + 0, t));
        float d1 = elu(bb[4 * j4 + 1] + dot64(wt, 4 * j4 + 1, t));
        float d2 = elu(bb[4 * j4 + 2] + dot64(wt, 4 * j4 + 2, t));
        float d3 = elu(bb[4 * j4 + 3] + dot64(wt, 4 * j4 + 3, t));
        out[j4] = make_float4(d0, d1, d2, d3);
    }
}

// ---------------- mean pool per graph (batch sorted -> binary search bounds) ----
__global__ void pool_k(const float4* __restrict__ h, const int* __restrict__ batch,
                       float4* __restrict__ pooled) {
    int gph = blockIdx.x;
    int tid = threadIdx.x;          // 256
    int lo = 0, hi = N_NODES;
    while (lo < hi) { int mid = (lo + hi) >> 1; if (batch[mid] < gph) lo = mid + 1; else hi = mid; }
    int start = lo;
    hi = N_NODES;
    while (lo < hi) { int mid = (lo + hi) >> 1; if (batch[mid] < gph + 1) lo = mid + 1; else hi = mid; }
    int end = lo;
    int q = tid & 15, r = tid >> 4;
    float4 acc = make_float4(0.f, 0.f, 0.f, 0.f);
    for (int n = start + r; n < end; n += 16) {
        float4 v = h[n * 16 + q];
        acc.x += v.x; acc.y += v.y; acc.z += v.z; acc.w += v.w;
    }
    __shared__ float4 red[256];
    red[tid] = acc;
    __syncthreads();
    for (int s = 8; s > 0; s >>= 1) {
        if (r < s) {
            float4 o = red[(r + s) * 16 + q];
            float4 m = red[r * 16 + q];
            m.x += o.x; m.y += o.y; m.z += o.z; m.w += o.w;
            red[r * 16 + q] = m;
        }
        __syncthreads();
    }
    if (r == 0) {
        float invc = 1.0f / fmaxf((float)(end - start), 1.0f);
        float4 m = red[q];
        m.x *= invc; m.y *= invc; m.z *= invc; m.w *= invc;
        pooled[gph * 16 + q] = m;
    }
}

// ---------------- readout head: 128 graphs, one lane each ----------------
__global__ void head_k(const float* __restrict__ pooled,
    const float* __restrict__ Wr1, const float* __restrict__ br1,
    const float* __restrict__ Wr2, const float* __restrict__ br2,
    const float* __restrict__ Wo,  const float* __restrict__ bo,
    float* __restrict__ out) {
    __shared__ float w1t[64 * WP];
    __shared__ float w2t[64 * WP];
    __shared__ float b1s[64], b2s[64], wos[64];
    int tid = threadIdx.x;   // 128
    for (int idx = tid; idx < 4096; idx += 128) {
        int k = idx >> 6, j = idx & 63;
        w1t[j * WP + k] = Wr1[idx];
        w2t[j * WP + k] = Wr2[idx];
    }
    if (tid < 64) { b1s[tid] = br1[tid]; b2s[tid] = br2[tid]; wos[tid] = Wo[tid]; }
    __syncthreads();
    int gph = tid;  // 0..127
    float t[64], y[64];
    const float4* pp = (const float4*)(pooled + gph * 64);
    #pragma unroll
    for (int q = 0; q < 16; ++q) {
        float4 v = pp[q];
        t[4 * q + 0] = v.x; t[4 * q + 1] = v.y; t[4 * q + 2] = v.z; t[4 * q + 3] = v.w;
    }
    #pragma unroll
    for (int j = 0; j < 64; ++j) y[j] = elu(b1s[j] + dot64(w1t, j, t));
    float o = bo[0];
    #pragma unroll
    for (int j = 0; j < 64; ++j) o += (b2s[j] + dot64(w2t, j, y)) * wos[j];
    out[gph] = o;
}

extern "C" void kernel_launch(void* const* d_in, const int* in_sizes, int n_in,
                              void* d_out, int out_size, void* d_ws, size_t ws_size,
                              hipStream_t stream) {
    const int*   x     = (const int*)d_in[0];
    const int*   ei    = (const int*)d_in[1];
    const int*   batch = (const int*)d_in[2];
    const float* emb   = (const float*)d_in[3];
    const float* P[24];
    for (int i = 0; i < 24; ++i) P[i] = (const float*)d_in[4 + i];

    char* ws = (char*)d_ws;
    float* h      = (float*)(ws + 0);           // (N+1) rows x 256B = 25.6 MB + 256B
    float* agg    = (float*)(ws + 26000000);    // 25.6 MB (doubles as y buffer)
    int*   adj    = (int*)  (ws + 52000000);    // 25.6 MB (N*CAP)
    int*   cnt    = (int*)  (ws + 78000000);    // 0.4 MB
    float* pooled = (float*)(ws + 78400000);    // 32 KB

    hipMemsetAsync(cnt, 0, N_NODES * sizeof(int), stream);
    hipMemsetAsync(h + N_NODES * 64, 0, 64 * sizeof(float), stream);  // sentinel row
    scatter_k<<<(N_EDGES + 255) / 256, 256, 0, stream>>>(ei, cnt, adj);
    pad_k<<<(N_NODES + 255) / 256, 256, 0, stream>>>(cnt, adj);
    embed_k<<<(N_NODES * 16 + 255) / 256, 256, 0, stream>>>(x, (const float4*)emb, (float4*)h);
    for (int L = 0; L < 3; ++L) {
        const float* const* p = P + 6 * L;
        agg_k<<<(N_NODES * 16 + 255) / 256, 256, 0, stream>>>(
            (const float4*)h, adj, cnt, (float4*)agg);
        mlpA_k<<<(N_NODES + 255) / 256, 256, 0, stream>>>(agg, p[0], p[1], p[2], p[3]);
        mlpB_k<<<(N_NODES + 255) / 256, 256, 0, stream>>>(agg, h, p[4], p[5]);
    }
    pool_k<<<G_GRAPHS, 256, 0, stream>>>((const float4*)h, batch, (float4*)pooled);
    head_k<<<1, 128, 0, stream>>>(pooled, P[18], P[19], P[20], P[21], P[22], P[23],
                                  (float*)d_out);
}